// Round 1
// baseline (99.631 us; speedup 1.0000x reference)
//
#include <hip/hip_runtime.h>
#include <hip/hip_bf16.h>

// CrossCCC: out = 1 - mean_n( 2*cov(n) / (var_gt + var_pred(n) + (mean_gt-mean_pred(n))^2) )
// cov(n)*T = C[n] - mean_gt*S(n);  C[n] = sum_j pred[j]*gt[j+n]
// S(n) = sum_pred_total - tail_s(n), Q(n) = sumsq_pred_total - tail_q(n)
//
// ws layout (floats): [0..255] = C[lag] partial-accumulated via atomics
//                     [256]=sum_pred [257]=sumsq_pred [258]=sum_gt [259]=sumsq_gt

#define T_CHUNK 1024
#define GT_N (T_CHUNK + 260)
#define NLAG 256
#define N_USED_LAGS 250

__global__ __launch_bounds__(256) void ccc_main(const float* __restrict__ pred,
                                                const float* __restrict__ gt,
                                                float* __restrict__ ws, int T) {
    __shared__ __align__(16) float s_pred[T_CHUNK];
    __shared__ __align__(16) float s_gt[GT_N + 4];
    __shared__ __align__(16) float s_acc[4][NLAG];
    __shared__ float s_red[4][4];

    const int tid = threadIdx.x;
    const int j0 = blockIdx.x * T_CHUNK;

    // ---- stage to LDS (zero-pad past T) + per-thread scalar partials ----
    float sp = 0.f, qp = 0.f, sg = 0.f, qg = 0.f;
    for (int i = tid; i < T_CHUNK; i += 256) {
        int g = j0 + i;
        float v = (g < T) ? pred[g] : 0.f;
        s_pred[i] = v;
        sp += v; qp += v * v;
    }
    for (int i = tid; i < GT_N; i += 256) {
        int g = j0 + i;
        float v = (g < T) ? gt[g] : 0.f;
        s_gt[i] = v;
        if (i < T_CHUNK) { sg += v; qg += v * v; }  // each gt elem counted once grid-wide
    }
    __syncthreads();

    // ---- cross-correlation: lane owns lags 4*lane..4*lane+3, wave owns a j-quarter ----
    const int wave = tid >> 6;
    const int lane = tid & 63;
    const int jb = wave * (T_CHUNK / 4);
    const int je = jb + (T_CHUNK / 4);
    const int base = 4 * lane;

    float4 acc = make_float4(0.f, 0.f, 0.f, 0.f);
    float4 wlo = *(const float4*)&s_gt[jb + base];
    float4 whi = *(const float4*)&s_gt[jb + base + 4];
    #pragma unroll 2
    for (int j = jb; j < je; j += 4) {
        float4 nxt = *(const float4*)&s_gt[j + base + 8];   // prefetch next window quad
        float4 p   = *(const float4*)&s_pred[j];            // wave-broadcast read
        // acc_k += pred[j+i] * gt[j+i + base + k]  (i,k in 0..3) -> window w0..w6
        acc.x += p.x * wlo.x; acc.y += p.x * wlo.y; acc.z += p.x * wlo.z; acc.w += p.x * wlo.w;
        acc.x += p.y * wlo.y; acc.y += p.y * wlo.z; acc.z += p.y * wlo.w; acc.w += p.y * whi.x;
        acc.x += p.z * wlo.z; acc.y += p.z * wlo.w; acc.z += p.z * whi.x; acc.w += p.z * whi.y;
        acc.x += p.w * wlo.w; acc.y += p.w * whi.x; acc.z += p.w * whi.y; acc.w += p.w * whi.z;
        wlo = whi; whi = nxt;
    }
    *(float4*)&s_acc[wave][base] = acc;

    // ---- scalar partials: wave shuffle-reduce then cross-wave via LDS ----
    for (int off = 32; off > 0; off >>= 1) {
        sp += __shfl_down(sp, off, 64);
        qp += __shfl_down(qp, off, 64);
        sg += __shfl_down(sg, off, 64);
        qg += __shfl_down(qg, off, 64);
    }
    if (lane == 0) {
        s_red[wave][0] = sp; s_red[wave][1] = qp;
        s_red[wave][2] = sg; s_red[wave][3] = qg;
    }
    __syncthreads();

    // ---- cross-wave lag reduce + one atomic per lag per block ----
    float lagsum = s_acc[0][tid] + s_acc[1][tid] + s_acc[2][tid] + s_acc[3][tid];
    atomicAdd(&ws[tid], lagsum);  // slots 250..255 are dead but reserved
    if (tid < 4) {
        float v = s_red[0][tid] + s_red[1][tid] + s_red[2][tid] + s_red[3][tid];
        atomicAdd(&ws[NLAG + tid], v);
    }
}

__global__ __launch_bounds__(256) void ccc_finalize(const float* __restrict__ pred,
                                                    const float* __restrict__ ws,
                                                    float* __restrict__ out, int T) {
    __shared__ float s_tail[256];  // s_tail[i] = pred[T-256+i]
    __shared__ float s_sum[256];
    const int t = threadIdx.x;
    {
        int g = T - 256 + t;
        s_tail[t] = (g >= 0 && g < T) ? pred[g] : 0.f;
    }
    __syncthreads();

    const float sum_pred = ws[256], sumsq_pred = ws[257];
    const float sum_gt = ws[258], sumsq_gt = ws[259];
    const float Tf = (float)T;
    const float mean_gt = sum_gt / Tf;
    const float var_gt = (sumsq_gt - sum_gt * sum_gt / Tf) / (Tf - 1.f);

    float ccc = 0.f;
    if (t < N_USED_LAGS) {
        float tail_s = 0.f, tail_q = 0.f;
        for (int i = 1; i <= t; ++i) {
            float v = s_tail[256 - i];           // pred[T-i]
            tail_s += v; tail_q += v * v;
        }
        float S = sum_pred - tail_s;
        float Q = sumsq_pred - tail_q;
        float mean_p = S / Tf;
        float var_p = (Q - S * S / Tf) / (Tf - 1.f);
        float cov = (ws[t] - mean_gt * S) / Tf;
        float dm = mean_gt - mean_p;
        float denom = var_gt + var_p + dm * dm;
        ccc = 2.f * cov / denom;
    }
    s_sum[t] = ccc;
    __syncthreads();
    for (int s = 128; s > 0; s >>= 1) {
        if (t < s) s_sum[t] += s_sum[t + s];
        __syncthreads();
    }
    if (t == 0) out[0] = 1.f - s_sum[0] / (float)N_USED_LAGS;
}

extern "C" void kernel_launch(void* const* d_in, const int* in_sizes, int n_in,
                              void* d_out, int out_size, void* d_ws, size_t ws_size,
                              hipStream_t stream) {
    const float* pred = (const float*)d_in[0];
    const float* gt   = (const float*)d_in[1];
    float* out = (float*)d_out;
    float* ws  = (float*)d_ws;
    const int T = in_sizes[0];

    hipMemsetAsync(ws, 0, (NLAG + 4) * sizeof(float), stream);
    const int nb = (T + T_CHUNK - 1) / T_CHUNK;
    ccc_main<<<nb, 256, 0, stream>>>(pred, gt, ws, T);
    ccc_finalize<<<1, 256, 0, stream>>>(pred, ws, out, T);
}

// Round 2
// 84.955 us; speedup vs baseline: 1.1728x; 1.1728x over previous
//
#include <hip/hip_runtime.h>
#include <hip/hip_bf16.h>

// CrossCCC: out = 1 - mean_n( 2*cov(n) / (var_gt + var_pred(n) + (mean_gt-mean_pred(n))^2) )
// cov(n)*T = C[n] - mean_gt*S(n);  C[n] = sum_m pred[m]*gt[m+n]  (gt zero-padded past T)
// S(n) = sum_pred - tail_s(n), Q(n) = sumsq_pred - tail_q(n), tails from last n pred elems.
//
// Two-phase deterministic reduction, NO global atomics (R0's 99.6us was dominated by
// 977x256 same-line atomicAdds serializing at ~16 TCC lines).
//
// ws layout (floats):
//   [c*256 + lag]                 c in [0,nch): per-chunk lag partial C[lag]   (nch=489)
//   [STATS_OFF + stat*512 + c]    stat in {sum_p, sumsq_p, sum_gt, sumsq_gt}
// Requires nch <= 512 (T <= 1,048,576; here T = 1e6).

#define TC 2048
#define NLAG 256
#define NUSED 250
#define GT4 (TC / 4 + 66)           // 578 float4s of gt staged (255-lag halo + window prefetch)
#define STATS_OFF (512 * NLAG)
#define STATS_PITCH 512

__device__ __forceinline__ float4 ld_gt_sw(const float* s_gt, int i4) {
    int s = i4 ^ ((i4 >> 3) & 7);   // XOR swizzle: makes 32B-lane-stride reads conflict-free
    return *(const float4*)&s_gt[4 * s];
}

__global__ __launch_bounds__(256) void ccc_main(const float* __restrict__ pred,
                                                const float* __restrict__ gt,
                                                float* __restrict__ ws, int T) {
    __shared__ __align__(16) float s_pred[TC];
    __shared__ __align__(16) float s_gt[GT4 * 4];
    __shared__ __align__(16) float s_acc[8][NLAG];
    __shared__ float s_red[4][4];

    const int tid = threadIdx.x;
    const int c = blockIdx.x;
    const int j0 = c * TC;

    // ---- stage to LDS (zero-pad past T; T%4==0 so float4 guards are whole) ----
    float sp = 0.f, qp = 0.f, sg = 0.f, qg = 0.f;
    #pragma unroll 2
    for (int i4 = tid; i4 < TC / 4; i4 += 256) {
        int g = j0 + 4 * i4;
        float4 v = make_float4(0.f, 0.f, 0.f, 0.f);
        if (g + 3 < T) v = *(const float4*)&pred[g];
        *(float4*)&s_pred[4 * i4] = v;
        sp += v.x + v.y + v.z + v.w;
        qp += v.x * v.x + v.y * v.y + v.z * v.z + v.w * v.w;
    }
    #pragma unroll 2
    for (int i4 = tid; i4 < GT4; i4 += 256) {
        int g = j0 + 4 * i4;
        float4 v = make_float4(0.f, 0.f, 0.f, 0.f);
        if (g + 3 < T) v = *(const float4*)&gt[g];
        int s = i4 ^ ((i4 >> 3) & 7);
        *(float4*)&s_gt[4 * s] = v;
        if (i4 < TC / 4) {          // each gt elem counted exactly once grid-wide
            sg += v.x + v.y + v.z + v.w;
            qg += v.x * v.x + v.y * v.y + v.z * v.z + v.w * v.w;
        }
    }
    __syncthreads();

    // ---- cross-correlation: half-wave sub=tid>>5 owns j in [sub*256, sub*256+256),
    //      lane l=tid&31 owns 8 lags [8l, 8l+8); 12-float register sliding window ----
    const int sub = tid >> 5;
    const int l = tid & 31;
    int gi = sub * 64 + 2 * l;      // float4 index of window start in s_gt
    const int pi0 = sub * 64;       // float4 index of pred

    float w[12];
    {
        float4 a = ld_gt_sw(s_gt, gi);
        float4 b = ld_gt_sw(s_gt, gi + 1);
        float4 d = ld_gt_sw(s_gt, gi + 2);
        w[0] = a.x; w[1] = a.y; w[2] = a.z; w[3] = a.w;
        w[4] = b.x; w[5] = b.y; w[6] = b.z; w[7] = b.w;
        w[8] = d.x; w[9] = d.y; w[10] = d.z; w[11] = d.w;
    }
    float acc[8] = {0.f, 0.f, 0.f, 0.f, 0.f, 0.f, 0.f, 0.f};

    #pragma unroll 4
    for (int it = 0; it < 64; ++it) {
        float4 nw = ld_gt_sw(s_gt, gi + 3 + it);            // prefetch next window quad
        float4 p = *(const float4*)&s_pred[4 * (pi0 + it)]; // half-wave broadcast
        #pragma unroll
        for (int k = 0; k < 8; ++k) {
            acc[k] = fmaf(p.x, w[k], acc[k]);
            acc[k] = fmaf(p.y, w[k + 1], acc[k]);
            acc[k] = fmaf(p.z, w[k + 2], acc[k]);
            acc[k] = fmaf(p.w, w[k + 3], acc[k]);
        }
        #pragma unroll
        for (int i = 0; i < 8; ++i) w[i] = w[i + 4];
        w[8] = nw.x; w[9] = nw.y; w[10] = nw.z; w[11] = nw.w;
    }

    // ---- scalar stats: wave shuffle-reduce ----
    const int wv = tid >> 6, ln = tid & 63;
    #pragma unroll
    for (int off = 32; off > 0; off >>= 1) {
        sp += __shfl_down(sp, off, 64);
        qp += __shfl_down(qp, off, 64);
        sg += __shfl_down(sg, off, 64);
        qg += __shfl_down(qg, off, 64);
    }
    if (ln == 0) { s_red[wv][0] = sp; s_red[wv][1] = qp; s_red[wv][2] = sg; s_red[wv][3] = qg; }

    #pragma unroll
    for (int k = 0; k < 8; ++k) s_acc[sub][8 * l + k] = acc[k];
    __syncthreads();

    // ---- per-block combine, plain coalesced stores (no atomics) ----
    float lagsum = 0.f;
    #pragma unroll
    for (int s = 0; s < 8; ++s) lagsum += s_acc[s][tid];
    ws[c * NLAG + tid] = lagsum;

    if (tid < 4) {
        ws[STATS_OFF + tid * STATS_PITCH + c] =
            s_red[0][tid] + s_red[1][tid] + s_red[2][tid] + s_red[3][tid];
    }
}

__global__ __launch_bounds__(1024) void ccc_finalize(const float* __restrict__ pred,
                                                     const float* __restrict__ ws,
                                                     float* __restrict__ out, int T, int nch) {
    __shared__ float s_part[4][NLAG];
    __shared__ float s_stats[4];
    __shared__ float s_tail[NLAG];
    __shared__ float s_sum[NLAG];

    const int t = threadIdx.x;
    const int q = t >> 8, lag = t & 255;

    // quarter q sums chunks c = q, q+4, ... : each iter reads one contiguous 1KB row
    float sum = 0.f;
    #pragma unroll 4
    for (int c = q; c < nch; c += 4) sum += ws[c * NLAG + lag];
    s_part[q][lag] = sum;

    if (t < 256) {
        int st = t >> 6, ln = t & 63;
        float s = 0.f;
        for (int c = ln; c < nch; c += 64) s += ws[STATS_OFF + st * STATS_PITCH + c];
        #pragma unroll
        for (int off = 32; off > 0; off >>= 1) s += __shfl_down(s, off, 64);
        if (ln == 0) s_stats[st] = s;
        int g = T - NLAG + t;
        s_tail[t] = (g >= 0 && g < T) ? pred[g] : 0.f;
    }
    __syncthreads();

    if (t < 256) {
        float lagC = s_part[0][t] + s_part[1][t] + s_part[2][t] + s_part[3][t];
        float v = 0.f;
        if (t < NUSED) {
            const float Tf = (float)T;
            float sum_pred = s_stats[0], sumsq_pred = s_stats[1];
            float sum_gt = s_stats[2], sumsq_gt = s_stats[3];
            float mean_gt = sum_gt / Tf;
            float var_gt = (sumsq_gt - sum_gt * sum_gt / Tf) / (Tf - 1.f);
            float tail_s = 0.f, tail_q = 0.f;
            for (int i = 1; i <= t; ++i) {
                float x = s_tail[NLAG - i];      // pred[T-i]
                tail_s += x; tail_q += x * x;
            }
            float S = sum_pred - tail_s;
            float Q = sumsq_pred - tail_q;
            float mean_p = S / Tf;
            float var_p = (Q - S * S / Tf) / (Tf - 1.f);
            float cov = (lagC - mean_gt * S) / Tf;
            float dm = mean_gt - mean_p;
            v = 2.f * cov / (var_gt + var_p + dm * dm);
        }
        s_sum[t] = v;
    }
    __syncthreads();
    for (int s = 128; s > 0; s >>= 1) {
        if (t < s) s_sum[t] += s_sum[t + s];
        __syncthreads();
    }
    if (t == 0) out[0] = 1.f - s_sum[0] / (float)NUSED;
}

extern "C" void kernel_launch(void* const* d_in, const int* in_sizes, int n_in,
                              void* d_out, int out_size, void* d_ws, size_t ws_size,
                              hipStream_t stream) {
    const float* pred = (const float*)d_in[0];
    const float* gt   = (const float*)d_in[1];
    float* out = (float*)d_out;
    float* ws  = (float*)d_ws;
    const int T = in_sizes[0];
    const int nch = (T + TC - 1) / TC;   // 489 for T=1e6 (must be <= 512)

    ccc_main<<<nch, 256, 0, stream>>>(pred, gt, ws, T);
    ccc_finalize<<<1, 1024, 0, stream>>>(pred, ws, out, T, nch);
}